// Round 1
// baseline (242.289 us; speedup 1.0000x reference)
//
#include <hip/hip_runtime.h>

// LinearSpline forward, C=64 channels, SIZE=51 knots, RANGE=1 -> GRID=0.04, odd SIZE (no EVEN shift)
#define C_NUM 64
#define S_SIZE 51

// f32 constants matching the JAX reference's f32 arithmetic:
//   GRID (double 0.04) cast to f32            = 0.04f
//   -(GRID*25) = -1.0000000000000002 -> f32   = -1.0f ; /0.04f rounds to exactly -25.0f
//   GRID*24 = 0.96000000000000002 -> f32      = 0.96f ; /0.04f == 24.0f EXACTLY (0.04f*24 == 0.96f bitwise)
// => floor(clip(xs,-1,0.96)/GRID) == floor(clip(xs/GRID, -25.0f, 24.0f)) for all xs (division monotone).
#define GRID_F   0.04f
#define Q_LO    -25.0f
#define Q_HI     24.0f

__global__ __launch_bounds__(256) void linearspline_fwd(
    const float* __restrict__ x,
    const float* __restrict__ coef,     // [C_NUM * S_SIZE] raw coefficients
    const float* __restrict__ scale,    // [C_NUM]
    float* __restrict__ out,
    int nvec)                           // number of float4 vectors
{
    __shared__ float s_cs[C_NUM * S_SIZE];   // raw coeffs
    __shared__ float s_cv[C_NUM * S_SIZE];   // projected (Lipschitz) coeffs
    __shared__ float s_s[C_NUM];
    __shared__ float s_inv[C_NUM];

    // stage raw coefficients (coalesced)
    for (int i = threadIdx.x; i < C_NUM * S_SIZE; i += 256) s_cs[i] = coef[i];
    if (threadIdx.x < C_NUM) {
        float s = scale[threadIdx.x];
        s_s[threadIdx.x]   = s;
        s_inv[threadIdx.x] = 1.0f / s;
    }
    __syncthreads();

    // Lipschitz projection: slopes = clip(diff, 0, GRID); cumsum; center at knot 25.
    // One thread per channel; lane t hits LDS word-stride 51 (gcd(51,32)=1 -> 2-way max, free).
    if (threadIdx.x < C_NUM) {
        const float* p = &s_cs[threadIdx.x * S_SIZE];
        float*       q = &s_cv[threadIdx.x * S_SIZE];
        float acc = 0.0f;
        q[0] = 0.0f;
        for (int j = 0; j < S_SIZE - 1; ++j) {
            float sl = p[j + 1] - p[j];
            sl = fminf(fmaxf(sl, 0.0f), GRID_F);
            acc += sl;
            q[j + 1] = acc;
        }
        float ctr = q[S_SIZE / 2];
        for (int j = 0; j < S_SIZE; ++j) q[j] -= ctr;
    }
    __syncthreads();

    const float4* xv = (const float4*)x;
    float4*       ov = (float4*)out;
    const int stride = gridDim.x * blockDim.x;

    for (int i = blockIdx.x * blockDim.x + threadIdx.x; i < nvec; i += stride) {
        // element base = i*4; H*W = 16384 elems/channel-row -> channel = (i*4/16384) % 64
        const int c      = (i >> 12) & (C_NUM - 1);
        const float s    = s_s[c];
        const float inv  = s_inv[c];
        const float* cvc = &s_cv[c * S_SIZE];

        float4 v = xv[i];
        float4 r;
        float* vp = (float*)&v;
        float* rp = (float*)&r;
#pragma unroll
        for (int k = 0; k < 4; ++k) {
            float xs = vp[k] * s;
            float d  = xs / GRID_F;                     // exact f32 division (matches ref semantics)
            float dc = fminf(fmaxf(d, Q_LO), Q_HI);     // == clip(xs,-1,0.96)/GRID under f32 (see header note)
            float fl = floorf(dc);
            float fr = d - fl;                          // ref: unclamped quotient minus floored
            int   il = 25 + (int)fl;                    // in [0, 49]
            float a  = cvc[il];
            float b  = cvc[il + 1];
            rp[k] = (b * fr + a * (1.0f - fr)) * inv;
        }
        ov[i] = r;
    }
}

extern "C" void kernel_launch(void* const* d_in, const int* in_sizes, int n_in,
                              void* d_out, int out_size, void* d_ws, size_t ws_size,
                              hipStream_t stream) {
    const float* x     = (const float*)d_in[0];
    const float* coef  = (const float*)d_in[1];
    const float* scale = (const float*)d_in[2];
    float*       out   = (float*)d_out;

    const int n    = in_sizes[0];        // 32*64*128*128 = 33,554,432 (divisible by 4)
    const int nvec = n >> 2;

    int blocks = (nvec + 255) / 256;
    if (blocks > 2048) blocks = 2048;    // grid-stride; ~8 blocks/CU

    linearspline_fwd<<<blocks, 256, 0, stream>>>(x, coef, scale, out, nvec);
}